// Round 2
// baseline (983.766 us; speedup 1.0000x reference)
//
#include <hip/hip_runtime.h>
#include <hip/hip_fp16.h>

#define BB 512
#define NN 200
#define FF 16
#define WW 256
#define DD 5
#define LATD 128
#define ALPHA 0.2f
#define NT 512     // threads per block (8 waves)
#define KT 32      // K-chunk staged in LDS

struct __align__(16) Lds {
    float gbuf[KT * WW];          // 32768 B  (G chunk; layer0: Gamma0 [0..4095] + compacted x [4096..7295])
    unsigned short h[NN * WW];    // 102400 B (activations, fp16)
    float mred[8 * WW];           // 8192 B   (cross-wave reduction scratch)
    float meanh[WW];              // 1024 B   (masked mean / pooled)
    float meanproj[WW];           // 1024 B   (mean @ L)
    float ybuf[2 * WW];           // 2048 B   (MLP ping-pong)
    int wavecnt[8];
};

__device__ __forceinline__ float lrelu(float v) { return v >= 0.f ? v : ALPHA * v; }

// fp16x2 <-> fp32 helpers (RNE)
__device__ __forceinline__ float2 up2(unsigned u) {
    __half2 h = *reinterpret_cast<__half2*>(&u);
    return __half22float2(h);
}
__device__ __forceinline__ unsigned pk2(float a, float b) {
    __half2 h = __floats2half2_rn(a, b);
    return *reinterpret_cast<unsigned*>(&h);
}

// column-sum of first NC cols of h over Nv rows -> outb (optionally * invNv)
template <int NC, bool DIV>
__device__ __forceinline__ void colsum(Lds& S, int tid, int lane, int wid, int Nv,
                                       float invNv, float* outb) {
    constexpr int CPL = NC / 64;
    float a[CPL];
#pragma unroll
    for (int c = 0; c < CPL; ++c) a[c] = 0.f;
    for (int r = wid; r < Nv; r += 8) {
        if constexpr (CPL == 4) {
            uint2 hv = *(const uint2*)&S.h[r * WW + 4 * lane];
            float2 f01 = up2(hv.x), f23 = up2(hv.y);
            a[0] += f01.x; a[1] += f01.y; a[2] += f23.x; a[3] += f23.y;
        } else {
            unsigned hv = *(const unsigned*)&S.h[r * WW + 2 * lane];
            float2 f01 = up2(hv);
            a[0] += f01.x; a[1] += f01.y;
        }
    }
#pragma unroll
    for (int c = 0; c < CPL; ++c) S.mred[wid * NC + CPL * lane + c] = a[c];
    __syncthreads();
    if (tid < NC) {
        float s = 0.f;
#pragma unroll
        for (int w2 = 0; w2 < 8; ++w2) s += S.mred[w2 * NC + tid];
        outb[tid] = DIV ? s * invNv : s;
    }
    __syncthreads();
}

// meanproj[0..NC) = meanh[0..K) @ L[K][NC]
__device__ __forceinline__ void mproj(Lds& S, const float* __restrict__ L, int tid, int K, int NC) {
    if (tid < NC) {
        float a = 0.f;
        for (int k = 0; k < K; ++k) a = fmaf(S.meanh[k], L[k * NC + tid], a);
        S.meanproj[tid] = a;
    }
    __syncthreads();
}

// in-place equivariant GEMM: h[0..Nv)[0..NC) = lrelu(h[0..Nv)[0..W) @ G[W][NC] - meanproj)
template <int NC>
__device__ __forceinline__ void eq_gemm(Lds& S, const float* __restrict__ G,
                                        int tid, int lane, int wid, int Nv) {
    constexpr int CPL = NC / 64;
    const int ntiles = (Nv + 63) >> 6;
    for (int t = 0; t < ntiles; ++t) {
        const int rbase = t * 64 + wid * 8;
        float acc[8][CPL];
#pragma unroll
        for (int r = 0; r < 8; ++r)
#pragma unroll
            for (int c = 0; c < CPL; ++c) acc[r][c] = 0.f;
        int hb[8];
#pragma unroll
        for (int r = 0; r < 8; ++r) {
            int row = rbase + r;
            hb[r] = (row < Nv ? row : Nv - 1) * WW;   // clamp reads; writes guarded
        }
        for (int kc = 0; kc < WW / KT; ++kc) {
            const float* Gs = G + kc * (KT * NC);
#pragma unroll
            for (int u = 0; u < (KT * NC) / (NT * 4); ++u) {
                int idx = (tid + u * NT) * 4;
                *(float4*)&S.gbuf[idx] = *(const float4*)&Gs[idx];
            }
            __syncthreads();
            const int k0 = kc * KT;
#pragma unroll
            for (int kk = 0; kk < KT; kk += 4) {
                float g[4][CPL];
#pragma unroll
                for (int d = 0; d < 4; ++d) {
                    if constexpr (CPL == 4) {
                        float4 gv = *(const float4*)&S.gbuf[(kk + d) * NC + 4 * lane];
                        g[d][0] = gv.x; g[d][1] = gv.y; g[d][2] = gv.z; g[d][3] = gv.w;
                    } else {
                        float2 gv = *(const float2*)&S.gbuf[(kk + d) * NC + 2 * lane];
                        g[d][0] = gv.x; g[d][1] = gv.y;
                    }
                }
#pragma unroll
                for (int r = 0; r < 8; ++r) {
                    uint2 hv = *(const uint2*)&S.h[hb[r] + k0 + kk];
                    float2 f01 = up2(hv.x), f23 = up2(hv.y);
                    float hf[4] = {f01.x, f01.y, f23.x, f23.y};
#pragma unroll
                    for (int d = 0; d < 4; ++d)
#pragma unroll
                        for (int c = 0; c < CPL; ++c)
                            acc[r][c] = fmaf(hf[d], g[d][c], acc[r][c]);
                }
            }
            __syncthreads();
        }
        // epilogue: subtract meanproj, lrelu, pack fp16, in-place store
        float mp[CPL];
        if constexpr (CPL == 4) {
            float4 m = *(const float4*)&S.meanproj[4 * lane];
            mp[0] = m.x; mp[1] = m.y; mp[2] = m.z; mp[3] = m.w;
        } else {
            float2 m = *(const float2*)&S.meanproj[2 * lane];
            mp[0] = m.x; mp[1] = m.y;
        }
#pragma unroll
        for (int r = 0; r < 8; ++r) {
            int row = rbase + r;
            if (row < Nv) {
                float o[CPL];
#pragma unroll
                for (int c = 0; c < CPL; ++c) o[c] = lrelu(acc[r][c] - mp[c]);
                if constexpr (CPL == 4) {
                    uint2 ov;
                    ov.x = pk2(o[0], o[1]);
                    ov.y = pk2(o[2], o[3]);
                    *(uint2*)&S.h[row * WW + 4 * lane] = ov;
                } else {
                    *(unsigned*)&S.h[row * WW + 2 * lane] = pk2(o[0], o[1]);
                }
            }
        }
    }
    __syncthreads();
}

__global__ __launch_bounds__(NT, 2) void deepset_kernel(
    const float* __restrict__ x,
    const float* __restrict__ Gamma0, const float* __restrict__ Lambda0,
    const float* __restrict__ Gmid, const float* __restrict__ Lmid,
    const float* __restrict__ GammaL, const float* __restrict__ LambdaL,
    const float* __restrict__ F0W, const float* __restrict__ F0b,
    const float* __restrict__ FmidW, const float* __restrict__ Fmidb,
    const float* __restrict__ FlastW, const float* __restrict__ Flastb,
    float* __restrict__ out) {
    __shared__ Lds S;
    const int tid = threadIdx.x, lane = tid & 63, wid = tid >> 6;
    const int b = blockIdx.x;

    // ---- mask + stable stream-compaction of valid rows into LDS (fp32) ----
    float* xl = &S.gbuf[4096];
    bool flag = false;
    const float* xr = x + ((size_t)b * NN + tid) * FF;
    if (tid < NN) {
#pragma unroll
        for (int f = 0; f < FF; ++f) flag |= (xr[f] != 0.0f);
    }
    unsigned long long bal = __ballot(flag);
    if (lane == 0) S.wavecnt[wid] = __popcll(bal);
    __syncthreads();
    int basec = 0, tot = 0;
#pragma unroll
    for (int w2 = 0; w2 < 8; ++w2) {
        int c = S.wavecnt[w2];
        if (w2 < wid) basec += c;
        tot += c;
    }
    const int Nv = tot;
    const float invNv = 1.0f / (float)Nv;
    if (flag) {
        int pos = basec + __popcll(bal & ((1ull << lane) - 1ull));
        float4* dst = (float4*)&xl[pos * FF];
        const float4* src = (const float4*)xr;
        dst[0] = src[0]; dst[1] = src[1]; dst[2] = src[2]; dst[3] = src[3];
    }
    // stage Gamma0 (16x256) into gbuf[0..4095]
#pragma unroll
    for (int u = 0; u < 2; ++u) {
        int idx = (tid + u * NT) * 4;
        *(float4*)&S.gbuf[idx] = *(const float4*)&Gamma0[idx];
    }
    __syncthreads();

    // ---- layer 0: mean_x, meanproj, h = lrelu(x@Gamma0 - mean_x@Lambda0) ----
    {
        int rg = tid >> 4, f = tid & 15;
        float a = 0.f;
        for (int r = rg; r < Nv; r += 32) a += xl[r * FF + f];
        S.mred[rg * FF + f] = a;
    }
    __syncthreads();
    if (tid < FF) {
        float s = 0.f;
#pragma unroll
        for (int g2 = 0; g2 < 32; ++g2) s += S.mred[g2 * FF + tid];
        S.meanh[tid] = s * invNv;
    }
    __syncthreads();
    mproj(S, Lambda0, tid, FF, WW);
    for (int r = wid; r < Nv; r += 8) {
        float acc[4] = {0.f, 0.f, 0.f, 0.f};
#pragma unroll
        for (int f = 0; f < FF; ++f) {
            float xv = xl[r * FF + f];
            float4 gv = *(const float4*)&S.gbuf[f * WW + 4 * lane];
            acc[0] = fmaf(xv, gv.x, acc[0]);
            acc[1] = fmaf(xv, gv.y, acc[1]);
            acc[2] = fmaf(xv, gv.z, acc[2]);
            acc[3] = fmaf(xv, gv.w, acc[3]);
        }
        float4 mp = *(const float4*)&S.meanproj[4 * lane];
        uint2 ov;
        ov.x = pk2(lrelu(acc[0] - mp.x), lrelu(acc[1] - mp.y));
        ov.y = pk2(lrelu(acc[2] - mp.z), lrelu(acc[3] - mp.w));
        *(uint2*)&S.h[r * WW + 4 * lane] = ov;
    }
    __syncthreads();

    // ---- mid equivariant layers (W -> W), 3x ----
    for (int i = 0; i < DD - 2; ++i) {
        colsum<WW, true>(S, tid, lane, wid, Nv, invNv, S.meanh);
        mproj(S, Lmid + i * WW * WW, tid, WW, WW);
        eq_gemm<WW>(S, Gmid + i * WW * WW, tid, lane, wid, Nv);
    }

    // ---- last equivariant layer (W -> LAT) ----
    colsum<WW, true>(S, tid, lane, wid, Nv, invNv, S.meanh);
    mproj(S, LambdaL, tid, WW, LATD);
    eq_gemm<LATD>(S, GammaL, tid, lane, wid, Nv);

    // ---- pooled = sum over valid rows ----
    colsum<LATD, false>(S, tid, lane, wid, Nv, invNv, S.meanh);

    // ---- MLP head ----
    if (tid < WW) {
        float a = F0b[tid];
        for (int k = 0; k < LATD; ++k) a = fmaf(S.meanh[k], F0W[k * WW + tid], a);
        S.ybuf[tid] = lrelu(a);
    }
    __syncthreads();
    int cur = 0;
    for (int i = 0; i < DD - 1; ++i) {
        if (tid < WW) {
            const float* Wm = FmidW + i * WW * WW;
            float a = Fmidb[i * WW + tid];
            for (int k = 0; k < WW; ++k) a = fmaf(S.ybuf[cur * WW + k], Wm[k * WW + tid], a);
            S.ybuf[(1 - cur) * WW + tid] = lrelu(a);
        }
        __syncthreads();
        cur = 1 - cur;
    }
    if (wid == 0) {
        float a0 = 0.f, a1 = 0.f;
        for (int k = lane; k < WW; k += 64) {
            float yv = S.ybuf[cur * WW + k];
            a0 = fmaf(yv, FlastW[2 * k], a0);
            a1 = fmaf(yv, FlastW[2 * k + 1], a1);
        }
#pragma unroll
        for (int off = 32; off > 0; off >>= 1) {
            a0 += __shfl_down(a0, off);
            a1 += __shfl_down(a1, off);
        }
        if (lane == 0) {
            a0 += Flastb[0];
            a1 += Flastb[1];
            float m = fmaxf(a0, a1);
            float e0 = expf(a0 - m), e1 = expf(a1 - m);
            float inv = 1.0f / (e0 + e1);
            out[2 * b] = e0 * inv;
            out[2 * b + 1] = e1 * inv;
        }
    }
}

extern "C" void kernel_launch(void* const* d_in, const int* in_sizes, int n_in,
                              void* d_out, int out_size, void* d_ws, size_t ws_size,
                              hipStream_t stream) {
    const float* x = (const float*)d_in[0];
    const float* Gamma0 = (const float*)d_in[1];
    const float* Lambda0 = (const float*)d_in[2];
    const float* Gmid = (const float*)d_in[3];
    const float* Lmid = (const float*)d_in[4];
    const float* GammaL = (const float*)d_in[5];
    const float* LambdaL = (const float*)d_in[6];
    const float* F0W = (const float*)d_in[7];
    const float* F0b = (const float*)d_in[8];
    const float* FmidW = (const float*)d_in[9];
    const float* Fmidb = (const float*)d_in[10];
    const float* FlastW = (const float*)d_in[11];
    const float* Flastb = (const float*)d_in[12];
    float* out = (float*)d_out;

    deepset_kernel<<<BB, NT, 0, stream>>>(x, Gamma0, Lambda0, Gmid, Lmid, GammaL, LambdaL,
                                          F0W, F0b, FmidW, Fmidb, FlastW, Flastb, out);
}

// Round 3
// 596.473 us; speedup vs baseline: 1.6493x; 1.6493x over previous
//
#include <hip/hip_runtime.h>
#include <hip/hip_fp16.h>
#include <stdint.h>

#define BB 512
#define NN 200
#define FF 16
#define WW 256
#define DD 5
#define LATD 128
#define ALPHA 0.2f
#define NT 512     // threads per block (8 waves)
#define NBLK 256   // persistent blocks (1 per CU)

typedef _Float16 f16x8 __attribute__((ext_vector_type(8)));
typedef float f32x4 __attribute__((ext_vector_type(4)));

// ws layout: [0..3] ticket counter, [16..] fp16 weight fragments:
//   Gmid frags:   3 layers x 65536 halfs   @ half-offset 0
//   GammaL frags: 32768 halfs              @ half-offset 196608
// frag addressing: ((chunk*(NC/16) + cf)*64 + lane)*8 halfs, lane=(n&15)+16*g, elem j <-> k=chunk*32+8g+j

struct __align__(16) Lds {
    unsigned short h[NN * WW];    // 102400 B fp16 activations, rows XOR-swizzled (byte ^= (row&7)<<4)
    float bf[2][4096];            // 2x16 KB: B-frag double buffer; at layer0: bf[0]=compacted x, bf[1]=Gamma0 raw
    float mred[2048];             // 8 KB reduction scratch
    float meanh[WW];              // masked mean / pooled
    float meanproj[WW];           // mean @ L
    float ybuf[2 * WW];           // MLP ping-pong
    int wavecnt[8];
    int ticket;
};

__device__ __forceinline__ float lrelu(float v) { return v >= 0.f ? v : ALPHA * v; }
__device__ __forceinline__ float2 up2(unsigned u) {
    __half2 h = *reinterpret_cast<__half2*>(&u);
    return __half22float2(h);
}
__device__ __forceinline__ unsigned pk2(float a, float b) {
    __half2 h = __floats2half2_rn(a, b);
    return *reinterpret_cast<unsigned*>(&h);
}
// byte offset of (row, colbyte) in S.h with bank-conflict XOR swizzle
__device__ __forceinline__ unsigned hoff(int row, int colbyte) {
    return (unsigned)(row * 512 + colbyte) ^ (unsigned)((row & 7) << 4);
}
__device__ __forceinline__ void gl_lds16(const void* g, void* l) {
    __builtin_amdgcn_global_load_lds((const __attribute__((address_space(1))) unsigned int*)g,
                                     (__attribute__((address_space(3))) unsigned int*)l, 16, 0, 0);
}

// ---- prep: pack G weights into fragment-ready fp16 in ws; also zero the ticket ----
__global__ __launch_bounds__(256) void prep_kernel(const float* __restrict__ Gmid,
                                                   const float* __restrict__ GammaL,
                                                   _Float16* __restrict__ wsf,
                                                   int* __restrict__ cnt) {
    int t = blockIdx.x * blockDim.x + threadIdx.x;
    if (t == 0) *cnt = 0;
    if (t < 24576) {                       // Gmid: 3 x (K=256 -> 32 octets) x (N=256)
        int layer = t / 8192, r = t % 8192;
        int a = r / 256, n = r % 256;      // k0 = 8a
        const float* G = Gmid + layer * 65536;
        f16x8 v;
#pragma unroll
        for (int j = 0; j < 8; ++j) v[j] = (_Float16)G[(8 * a + j) * 256 + n];
        int chunk = a >> 2, g = a & 3, cf = n >> 4, ln = (n & 15) + 16 * g;
        *(f16x8*)(wsf + (size_t)layer * 65536 + ((size_t)(chunk * 16 + cf) * 64 + ln) * 8) = v;
    } else {                               // GammaL: K=256, N=128
        int r = t - 24576;
        int a = r / 128, n = r % 128;
        f16x8 v;
#pragma unroll
        for (int j = 0; j < 8; ++j) v[j] = (_Float16)GammaL[(8 * a + j) * 128 + n];
        int chunk = a >> 2, g = a & 3, cf = n >> 4, ln = (n & 15) + 16 * g;
        *(f16x8*)(wsf + 196608 + ((size_t)(chunk * 8 + cf) * 64 + ln) * 8) = v;
    }
}

// column-sum of first NC cols of h over Nv rows -> outb (optionally * invNv)
template <int NC, bool DIV>
__device__ __forceinline__ void colsum(Lds& S, int tid, int lane, int wid, int Nv,
                                       float invNv, float* outb) {
    constexpr int CPL = NC / 64;
    float a[CPL];
#pragma unroll
    for (int c = 0; c < CPL; ++c) a[c] = 0.f;
    for (int r = wid; r < Nv; r += 8) {
        if constexpr (CPL == 4) {
            uint2 hv = *(const uint2*)((const char*)S.h + hoff(r, 8 * lane));
            float2 f01 = up2(hv.x), f23 = up2(hv.y);
            a[0] += f01.x; a[1] += f01.y; a[2] += f23.x; a[3] += f23.y;
        } else {
            unsigned hv = *(const unsigned*)((const char*)S.h + hoff(r, 4 * lane));
            float2 f01 = up2(hv);
            a[0] += f01.x; a[1] += f01.y;
        }
    }
#pragma unroll
    for (int c = 0; c < CPL; ++c) S.mred[wid * NC + CPL * lane + c] = a[c];
    __syncthreads();
    if (tid < NC) {
        float s = 0.f;
#pragma unroll
        for (int w2 = 0; w2 < 8; ++w2) s += S.mred[w2 * NC + tid];
        outb[tid] = DIV ? s * invNv : s;
    }
    __syncthreads();
}

// meanproj[0..NC) = meanh[0..K) @ L[K][NC], all NT threads (K split across NT/NC segments)
template <int K, int NC>
__device__ __forceinline__ void mproj_par(Lds& S, const float* __restrict__ L, int tid) {
    constexpr int SPLIT = NT / NC;
    constexpr int KS = K / SPLIT;
    const int c = tid & (NC - 1), seg = tid / NC;
    float a = 0.f;
    const float* Lp = L + (size_t)seg * KS * NC + c;
    const float* mh = S.meanh + seg * KS;
#pragma unroll 4
    for (int k = 0; k < KS; ++k) a = fmaf(mh[k], Lp[(size_t)k * NC], a);
    S.mred[seg * NC + c] = a;
    __syncthreads();
    if (tid < NC) {
        float s = 0.f;
#pragma unroll
        for (int q = 0; q < SPLIT; ++q) s += S.mred[q * NC + tid];
        S.meanproj[tid] = s;
    }
    __syncthreads();
}

// MFMA equivariant GEMM, in place: h[0..Nv)[0..NC) = lrelu(h[0..Nv)[0..256) @ G - meanproj)
// Wf: fragment-packed fp16 weights in ws. Waves: 2 rowgroups x 4 colgroups, one pass.
template <int NC>
__device__ __forceinline__ void eq_gemm_mfma(Lds& S, const _Float16* __restrict__ Wf,
                                             int tid, int lane, int wid, int Nv) {
    constexpr int CPW = NC / 64;           // colfrags per wave
    constexpr int CHB = NC * 64;           // bytes per k-chunk of fragments
    constexpr int INS = CHB / 8192;        // global_load_lds x16 per wave per chunk
    const int rg = wid >> 2, cg = wid & 3;
    const int RF = (Nv + 15) >> 4;         // rowfrags (<=13)
    const int nrf = (RF - rg + 1) >> 1;    // this wave's rowfrags (<=7)
    f32x4 acc[7][CPW];
#pragma unroll
    for (int i = 0; i < 7; ++i)
#pragma unroll
        for (int u = 0; u < CPW; ++u)
#pragma unroll
            for (int j = 0; j < 4; ++j) acc[i][u][j] = 0.f;
    // prologue: stage chunk 0 into bf[0]
    {
        const char* src = (const char*)Wf + wid * (CHB / 8) + lane * 16;
        char* dst = (char*)S.bf[0] + wid * (CHB / 8);
#pragma unroll
        for (int u = 0; u < INS; ++u) gl_lds16(src + u * 1024, dst + u * 1024);
    }
    asm volatile("s_waitcnt vmcnt(0)" ::: "memory");
    __syncthreads();
    for (int c = 0; c < 8; ++c) {
        const unsigned short* bbase = (const unsigned short*)S.bf[c & 1];
        if (c < 7) {  // issue next-chunk stage before compute (2-phase pipeline)
            const char* src = (const char*)Wf + (size_t)(c + 1) * CHB + wid * (CHB / 8) + lane * 16;
            char* dst = (char*)S.bf[(c + 1) & 1] + wid * (CHB / 8);
#pragma unroll
            for (int u = 0; u < INS; ++u) gl_lds16(src + u * 1024, dst + u * 1024);
        }
        f16x8 bfr[CPW];
#pragma unroll
        for (int u = 0; u < CPW; ++u)
            bfr[u] = *(const f16x8*)(bbase + ((size_t)(cg * CPW + u) * 64 + lane) * 8);
        const int kb = c * 64;             // k byte offset within row
#pragma unroll
        for (int i = 0; i < 7; ++i) {
            if (i < nrf) {
                int row = (rg + 2 * i) * 16 + (lane & 15);
                row = row < Nv ? row : Nv - 1;   // clamp reads; writes guarded
                f16x8 af = *(const f16x8*)((const char*)S.h + hoff(row, kb + ((lane >> 4) << 4)));
#pragma unroll
                for (int u = 0; u < CPW; ++u)
                    acc[i][u] = __builtin_amdgcn_mfma_f32_16x16x32_f16(af, bfr[u], acc[i][u], 0, 0, 0);
            }
        }
        asm volatile("s_waitcnt vmcnt(0)" ::: "memory");
        __syncthreads();                   // also guarantees all h reads done before epilogue writes
    }
    // epilogue: subtract meanproj, lrelu, fp16, in-place scatter (C/D: col=lane&15, row=4g+j)
    const int cl = lane & 15, g = lane >> 4;
    float mp[CPW];
#pragma unroll
    for (int u = 0; u < CPW; ++u) mp[u] = S.meanproj[(cg * CPW + u) * 16 + cl];
#pragma unroll
    for (int i = 0; i < 7; ++i) {
        if (i < nrf) {
            int rbase = (rg + 2 * i) * 16;
#pragma unroll
            for (int j = 0; j < 4; ++j) {
                int row = rbase + 4 * g + j;
                if (row < Nv) {
#pragma unroll
                    for (int u = 0; u < CPW; ++u) {
                        float o = lrelu(acc[i][u][j] - mp[u]);
                        *(_Float16*)((char*)S.h + hoff(row, ((cg * CPW + u) * 16 + cl) * 2)) = (_Float16)o;
                    }
                }
            }
        }
    }
    __syncthreads();
}

__global__ __launch_bounds__(NT, 2) void deepset_kernel(
    const float* __restrict__ x,
    const float* __restrict__ Gamma0, const float* __restrict__ Lambda0,
    const float* __restrict__ Lmid,
    const float* __restrict__ LambdaL,
    const float* __restrict__ F0W, const float* __restrict__ F0b,
    const float* __restrict__ FmidW, const float* __restrict__ Fmidb,
    const float* __restrict__ FlastW, const float* __restrict__ Flastb,
    int* __restrict__ cnt, const _Float16* __restrict__ wsf,
    float* __restrict__ out) {
    __shared__ Lds S;
    const int tid = threadIdx.x, lane = tid & 63, wid = tid >> 6;

    for (;;) {
        if (tid == 0) S.ticket = atomicAdd(cnt, 1);
        __syncthreads();
        const int b = S.ticket;
        if (b >= BB) break;

        // ---- mask + stable stream-compaction of valid rows into bf[0] (fp32) ----
        float* xl = S.bf[0];
        float* g0 = S.bf[1];
        bool flag = false;
        const float* xr = x + ((size_t)b * NN + tid) * FF;
        if (tid < NN) {
#pragma unroll
            for (int f = 0; f < FF; ++f) flag |= (xr[f] != 0.0f);
        }
        unsigned long long bal = __ballot(flag);
        if (lane == 0) S.wavecnt[wid] = __popcll(bal);
        __syncthreads();
        int basec = 0, tot = 0;
#pragma unroll
        for (int w2 = 0; w2 < 8; ++w2) {
            int c = S.wavecnt[w2];
            if (w2 < wid) basec += c;
            tot += c;
        }
        const int Nv = tot;
        const float invNv = 1.0f / (float)Nv;
        if (flag) {
            int pos = basec + __popcll(bal & ((1ull << lane) - 1ull));
            float4* dst = (float4*)&xl[pos * FF];
            const float4* src = (const float4*)xr;
            dst[0] = src[0]; dst[1] = src[1]; dst[2] = src[2]; dst[3] = src[3];
        }
        // stage Gamma0 raw fp32 (16x256) into bf[1]
#pragma unroll
        for (int u = 0; u < 2; ++u) {
            int e = (u * NT + tid) * 4;
            *(float4*)&g0[e] = *(const float4*)&Gamma0[e];
        }
        __syncthreads();

        // ---- layer 0: mean_x, meanproj, h = lrelu(x@Gamma0 - mean_x@Lambda0) ----
        {
            int rg2 = tid >> 4, f = tid & 15;
            float a = 0.f;
            for (int r = rg2; r < Nv; r += 32) a += xl[r * FF + f];
            S.mred[rg2 * FF + f] = a;
        }
        __syncthreads();
        if (tid < FF) {
            float s = 0.f;
#pragma unroll
            for (int g2 = 0; g2 < 32; ++g2) s += S.mred[g2 * FF + tid];
            S.meanh[tid] = s * invNv;
        }
        __syncthreads();
        mproj_par<FF, WW>(S, Lambda0, tid);
        for (int r = wid; r < Nv; r += 8) {
            float acc0[4] = {0.f, 0.f, 0.f, 0.f};
#pragma unroll
            for (int f = 0; f < FF; ++f) {
                float xv = xl[r * FF + f];
                float4 gv = *(const float4*)&g0[f * WW + 4 * lane];
                acc0[0] = fmaf(xv, gv.x, acc0[0]);
                acc0[1] = fmaf(xv, gv.y, acc0[1]);
                acc0[2] = fmaf(xv, gv.z, acc0[2]);
                acc0[3] = fmaf(xv, gv.w, acc0[3]);
            }
            float4 mp = *(const float4*)&S.meanproj[4 * lane];
            uint2 ov;
            ov.x = pk2(lrelu(acc0[0] - mp.x), lrelu(acc0[1] - mp.y));
            ov.y = pk2(lrelu(acc0[2] - mp.z), lrelu(acc0[3] - mp.w));
            *(uint2*)((char*)S.h + hoff(r, 8 * lane)) = ov;
        }
        __syncthreads();

        // ---- mid equivariant layers (W -> W), 3x, MFMA ----
        for (int i = 0; i < DD - 2; ++i) {
            colsum<WW, true>(S, tid, lane, wid, Nv, invNv, S.meanh);
            mproj_par<WW, WW>(S, Lmid + (size_t)i * WW * WW, tid);
            eq_gemm_mfma<WW>(S, wsf + (size_t)i * 65536, tid, lane, wid, Nv);
        }

        // ---- last equivariant layer (W -> LAT), MFMA ----
        colsum<WW, true>(S, tid, lane, wid, Nv, invNv, S.meanh);
        mproj_par<WW, LATD>(S, LambdaL, tid);
        eq_gemm_mfma<LATD>(S, wsf + 196608, tid, lane, wid, Nv);

        // ---- pooled = sum over valid rows ----
        colsum<LATD, false>(S, tid, lane, wid, Nv, invNv, S.meanh);

        // ---- MLP head (all 512 threads, K split in halves) ----
        {
            const int c = tid & 255, seg = tid >> 8;
            float a = 0.f;
            const float* Wp = F0W + (size_t)seg * 64 * WW + c;
            const float* ip = S.meanh + seg * 64;
#pragma unroll 4
            for (int k = 0; k < 64; ++k) a = fmaf(ip[k], Wp[(size_t)k * WW], a);
            S.mred[seg * WW + c] = a;
            __syncthreads();
            if (tid < WW) S.ybuf[tid] = lrelu(S.mred[tid] + S.mred[WW + tid] + F0b[tid]);
            __syncthreads();
        }
        int cur = 0;
        for (int i = 0; i < DD - 1; ++i) {
            const int c = tid & 255, seg = tid >> 8;
            const float* Wm = FmidW + (size_t)i * WW * WW;
            float a = 0.f;
            const float* Wp = Wm + (size_t)seg * 128 * WW + c;
            const float* ip = S.ybuf + cur * WW + seg * 128;
#pragma unroll 4
            for (int k = 0; k < 128; ++k) a = fmaf(ip[k], Wp[(size_t)k * WW], a);
            S.mred[seg * WW + c] = a;
            __syncthreads();
            if (tid < WW)
                S.ybuf[(1 - cur) * WW + tid] = lrelu(S.mred[tid] + S.mred[WW + tid] + Fmidb[i * WW + tid]);
            __syncthreads();
            cur = 1 - cur;
        }
        if (wid == 0) {
            float a0 = 0.f, a1 = 0.f;
            for (int k = lane; k < WW; k += 64) {
                float yv = S.ybuf[cur * WW + k];
                a0 = fmaf(yv, FlastW[2 * k], a0);
                a1 = fmaf(yv, FlastW[2 * k + 1], a1);
            }
#pragma unroll
            for (int off = 32; off > 0; off >>= 1) {
                a0 += __shfl_down(a0, off);
                a1 += __shfl_down(a1, off);
            }
            if (lane == 0) {
                a0 += Flastb[0];
                a1 += Flastb[1];
                float m = fmaxf(a0, a1);
                float e0 = expf(a0 - m), e1 = expf(a1 - m);
                float inv = 1.0f / (e0 + e1);
                out[2 * b] = e0 * inv;
                out[2 * b + 1] = e1 * inv;
            }
        }
        __syncthreads();
    }
}

extern "C" void kernel_launch(void* const* d_in, const int* in_sizes, int n_in,
                              void* d_out, int out_size, void* d_ws, size_t ws_size,
                              hipStream_t stream) {
    const float* x = (const float*)d_in[0];
    const float* Gamma0 = (const float*)d_in[1];
    const float* Lambda0 = (const float*)d_in[2];
    const float* Gmid = (const float*)d_in[3];
    const float* Lmid = (const float*)d_in[4];
    const float* GammaL = (const float*)d_in[5];
    const float* LambdaL = (const float*)d_in[6];
    const float* F0W = (const float*)d_in[7];
    const float* F0b = (const float*)d_in[8];
    const float* FmidW = (const float*)d_in[9];
    const float* Fmidb = (const float*)d_in[10];
    const float* FlastW = (const float*)d_in[11];
    const float* Flastb = (const float*)d_in[12];
    float* out = (float*)d_out;

    int* cnt = (int*)d_ws;
    _Float16* wsf = (_Float16*)((char*)d_ws + 16);

    prep_kernel<<<112, 256, 0, stream>>>(Gmid, GammaL, wsf, cnt);
    deepset_kernel<<<NBLK, NT, 0, stream>>>(x, Gamma0, Lambda0, Lmid, LambdaL,
                                            F0W, F0b, FmidW, Fmidb, FlastW, Flastb,
                                            cnt, wsf, out);
}

// Round 4
// 299.747 us; speedup vs baseline: 3.2820x; 1.9899x over previous
//
#include <hip/hip_runtime.h>
#include <hip/hip_fp16.h>
#include <stdint.h>

#define BB 512
#define NN 200
#define FF 16
#define WW 256
#define DD 5
#define LATD 128
#define ALPHA 0.2f
#define NT 512     // threads per block (8 waves)
#define NBLK 256   // persistent blocks (1 per CU)

typedef _Float16 f16x8 __attribute__((ext_vector_type(8)));
typedef float f32x4 __attribute__((ext_vector_type(4)));

// ws layout: [0..3] ticket counter, [16..] fp16 weight fragments:
//   Gmid frags:   3 layers x 65536 halfs   @ half-offset 0
//   GammaL frags: 32768 halfs              @ half-offset 196608
//   pooled fp32 [512][128]                 @ byte-offset 458768
// frag addressing: ((chunk*(NC/16) + cf)*64 + lane)*8 halfs, lane=(n&15)+16*g, elem j <-> k=chunk*32+8g+j

struct __align__(16) Lds {
    unsigned short h[NN * WW];    // 102400 B fp16 activations, rows XOR-swizzled (byte ^= (row&7)<<4)
    float g0[FF * WW];            // 16384 B (layer0: Gamma0 fp32)
    float xl[NN * FF];            // 12800 B (layer0: compacted x fp32)
    float mred[2048];             // 8192 B reduction scratch
    float meanh[WW];              // masked mean / pooled
    float meanproj[WW];           // mean @ L
    int wavecnt[8];
    int ticket;
};

__device__ __forceinline__ float lrelu(float v) { return v >= 0.f ? v : ALPHA * v; }
__device__ __forceinline__ float2 up2(unsigned u) {
    __half2 h = *reinterpret_cast<__half2*>(&u);
    return __half22float2(h);
}
__device__ __forceinline__ unsigned pk2(float a, float b) {
    __half2 h = __floats2half2_rn(a, b);
    return *reinterpret_cast<unsigned*>(&h);
}
// byte offset of (row, colbyte) in S.h with bank-conflict XOR swizzle
__device__ __forceinline__ unsigned hoff(int row, int colbyte) {
    return (unsigned)(row * 512 + colbyte) ^ (unsigned)((row & 7) << 4);
}

// ---- prep: pack G weights into fragment-ready fp16 in ws; also zero the ticket ----
__global__ __launch_bounds__(256) void prep_kernel(const float* __restrict__ Gmid,
                                                   const float* __restrict__ GammaL,
                                                   _Float16* __restrict__ wsf,
                                                   int* __restrict__ cnt) {
    int t = blockIdx.x * blockDim.x + threadIdx.x;
    if (t == 0) *cnt = 0;
    if (t < 24576) {                       // Gmid: 3 x (K=256 -> 32 octets) x (N=256)
        int layer = t / 8192, r = t % 8192;
        int a = r / 256, n = r % 256;      // k0 = 8a
        const float* G = Gmid + layer * 65536;
        f16x8 v;
#pragma unroll
        for (int j = 0; j < 8; ++j) v[j] = (_Float16)G[(8 * a + j) * 256 + n];
        int chunk = a >> 2, g = a & 3, cf = n >> 4, ln = (n & 15) + 16 * g;
        *(f16x8*)(wsf + (size_t)layer * 65536 + ((size_t)(chunk * 16 + cf) * 64 + ln) * 8) = v;
    } else {                               // GammaL: K=256, N=128
        int r = t - 24576;
        int a = r / 128, n = r % 128;
        f16x8 v;
#pragma unroll
        for (int j = 0; j < 8; ++j) v[j] = (_Float16)GammaL[(8 * a + j) * 128 + n];
        int chunk = a >> 2, g = a & 3, cf = n >> 4, ln = (n & 15) + 16 * g;
        *(f16x8*)(wsf + 196608 + ((size_t)(chunk * 8 + cf) * 64 + ln) * 8) = v;
    }
}

// column-sum of first NC cols of h over Nv rows -> outb (optionally * invNv)
template <int NC, bool DIV>
__device__ __forceinline__ void colsum(Lds& S, int tid, int lane, int wid, int Nv,
                                       float invNv, float* outb) {
    constexpr int CPL = NC / 64;
    float a[CPL];
#pragma unroll
    for (int c = 0; c < CPL; ++c) a[c] = 0.f;
    for (int r = wid; r < Nv; r += 8) {
        if constexpr (CPL == 4) {
            uint2 hv = *(const uint2*)((const char*)S.h + hoff(r, 8 * lane));
            float2 f01 = up2(hv.x), f23 = up2(hv.y);
            a[0] += f01.x; a[1] += f01.y; a[2] += f23.x; a[3] += f23.y;
        } else {
            unsigned hv = *(const unsigned*)((const char*)S.h + hoff(r, 4 * lane));
            float2 f01 = up2(hv);
            a[0] += f01.x; a[1] += f01.y;
        }
    }
#pragma unroll
    for (int c = 0; c < CPL; ++c) S.mred[wid * NC + CPL * lane + c] = a[c];
    __syncthreads();
    if (tid < NC) {
        float s = 0.f;
#pragma unroll
        for (int w2 = 0; w2 < 8; ++w2) s += S.mred[w2 * NC + tid];
        outb[tid] = DIV ? s * invNv : s;
    }
    __syncthreads();
}

// meanproj[0..NC) = meanh[0..K) @ L[K][NC], all NT threads (K split across NT/NC segments)
template <int K, int NC>
__device__ __forceinline__ void mproj_par(Lds& S, const float* __restrict__ L, int tid) {
    constexpr int SPLIT = NT / NC;
    constexpr int KS = K / SPLIT;
    const int c = tid & (NC - 1), seg = tid / NC;
    float a = 0.f;
    const float* Lp = L + (size_t)seg * KS * NC + c;
    const float* mh = S.meanh + seg * KS;
#pragma unroll
    for (int k = 0; k < KS; ++k) a = fmaf(mh[k], Lp[(size_t)k * NC], a);
    S.mred[seg * NC + c] = a;
    __syncthreads();
    if (tid < NC) {
        float s = 0.f;
#pragma unroll
        for (int q = 0; q < SPLIT; ++q) s += S.mred[q * NC + tid];
        S.meanproj[tid] = s;
    }
    __syncthreads();
}

// MFMA equivariant GEMM, in place: h[0..Nv)[0..NC) = lrelu(h[0..Nv)[0..256) @ G - meanproj)
// B-fragments read DIRECTLY from global (fragment-packed by prep; L2-warm, no LDS staging).
// 8 waves = 2 rowgroups x 4 colgroups; row passes of 8 rowfrags (acc[4][CPW] = 64 VGPR max).
template <int NC>
__device__ __forceinline__ void eq_gemm_mfma(Lds& S, const _Float16* __restrict__ Wf,
                                             int tid, int lane, int wid, int Nv) {
    constexpr int CPW = NC / 64;           // colfrags per wave
    const int rg = wid >> 2, cg = wid & 3;
    const int RF = (Nv + 15) >> 4;         // rowfrags (<=13)
    const int cl = lane & 15, g = lane >> 4;
    for (int p0 = 0; p0 < RF; p0 += 8) {
        f32x4 acc[4][CPW];
#pragma unroll
        for (int i = 0; i < 4; ++i)
#pragma unroll
            for (int u = 0; u < CPW; ++u)
#pragma unroll
                for (int j = 0; j < 4; ++j) acc[i][u][j] = 0.f;
#pragma unroll 4
        for (int c = 0; c < 8; ++c) {
            f16x8 bfr[CPW];
#pragma unroll
            for (int u = 0; u < CPW; ++u)
                bfr[u] = *(const f16x8*)(Wf + (((size_t)c * (NC / 16) + cg * CPW + u) * 64 + lane) * 8);
            const int kb = c * 64;         // k byte offset within row
#pragma unroll
            for (int i = 0; i < 4; ++i) {
                const int rf = p0 + rg + 2 * i;
                if (rf < RF) {
                    int row = rf * 16 + cl;
                    row = row < Nv ? row : Nv - 1;   // clamp reads; writes guarded
                    f16x8 af = *(const f16x8*)((const char*)S.h + hoff(row, kb + (g << 4)));
#pragma unroll
                    for (int u = 0; u < CPW; ++u)
                        acc[i][u] = __builtin_amdgcn_mfma_f32_16x16x32_f16(af, bfr[u], acc[i][u], 0, 0, 0);
                }
            }
        }
        __syncthreads();                   // all reads of old h done before in-place writes
        float mp[CPW];
#pragma unroll
        for (int u = 0; u < CPW; ++u) mp[u] = S.meanproj[(cg * CPW + u) * 16 + cl];
#pragma unroll
        for (int i = 0; i < 4; ++i) {
            const int rf = p0 + rg + 2 * i;
            if (rf < RF) {
#pragma unroll
                for (int j = 0; j < 4; ++j) {
                    int row = rf * 16 + 4 * g + j;
                    if (row < Nv) {
#pragma unroll
                        for (int u = 0; u < CPW; ++u) {
                            float o = lrelu(acc[i][u][j] - mp[u]);
                            *(_Float16*)((char*)S.h + hoff(row, ((cg * CPW + u) * 16 + cl) * 2)) = (_Float16)o;
                        }
                    }
                }
            }
        }
    }
    __syncthreads();
}

__global__ __launch_bounds__(NT, 1) void deepset_kernel(
    const float* __restrict__ x,
    const float* __restrict__ Gamma0, const float* __restrict__ Lambda0,
    const float* __restrict__ Lmid,
    const float* __restrict__ LambdaL,
    int* __restrict__ cnt, const _Float16* __restrict__ wsf,
    float* __restrict__ pooled) {
    __shared__ Lds S;
    const int tid = threadIdx.x, lane = tid & 63, wid = tid >> 6;

    for (;;) {
        if (tid == 0) S.ticket = atomicAdd(cnt, 1);
        __syncthreads();
        const int b = S.ticket;
        if (b >= BB) break;

        // ---- mask + stable stream-compaction of valid rows into xl (fp32) ----
        bool flag = false;
        const float* xr = x + ((size_t)b * NN + tid) * FF;
        if (tid < NN) {
#pragma unroll
            for (int f = 0; f < FF; ++f) flag |= (xr[f] != 0.0f);
        }
        unsigned long long bal = __ballot(flag);
        if (lane == 0) S.wavecnt[wid] = __popcll(bal);
        __syncthreads();
        int basec = 0, tot = 0;
#pragma unroll
        for (int w2 = 0; w2 < 8; ++w2) {
            int c = S.wavecnt[w2];
            if (w2 < wid) basec += c;
            tot += c;
        }
        const int Nv = tot;
        const float invNv = 1.0f / (float)Nv;
        if (flag) {
            int pos = basec + __popcll(bal & ((1ull << lane) - 1ull));
            float4* dst = (float4*)&S.xl[pos * FF];
            const float4* src = (const float4*)xr;
            dst[0] = src[0]; dst[1] = src[1]; dst[2] = src[2]; dst[3] = src[3];
        }
        // stage Gamma0 raw fp32 (16x256) into g0
#pragma unroll
        for (int u = 0; u < 2; ++u) {
            int e = (u * NT + tid) * 4;
            *(float4*)&S.g0[e] = *(const float4*)&Gamma0[e];
        }
        __syncthreads();

        // ---- layer 0: mean_x, meanproj, h = lrelu(x@Gamma0 - mean_x@Lambda0) ----
        {
            int rg2 = tid >> 4, f = tid & 15;
            float a = 0.f;
            for (int r = rg2; r < Nv; r += 32) a += S.xl[r * FF + f];
            S.mred[rg2 * FF + f] = a;
        }
        __syncthreads();
        if (tid < FF) {
            float s = 0.f;
#pragma unroll
            for (int g2 = 0; g2 < 32; ++g2) s += S.mred[g2 * FF + tid];
            S.meanh[tid] = s * invNv;
        }
        __syncthreads();
        mproj_par<FF, WW>(S, Lambda0, tid);
        for (int r = wid; r < Nv; r += 8) {
            float acc0[4] = {0.f, 0.f, 0.f, 0.f};
#pragma unroll
            for (int f = 0; f < FF; ++f) {
                float xv = S.xl[r * FF + f];
                float4 gv = *(const float4*)&S.g0[f * WW + 4 * lane];
                acc0[0] = fmaf(xv, gv.x, acc0[0]);
                acc0[1] = fmaf(xv, gv.y, acc0[1]);
                acc0[2] = fmaf(xv, gv.z, acc0[2]);
                acc0[3] = fmaf(xv, gv.w, acc0[3]);
            }
            float4 mp = *(const float4*)&S.meanproj[4 * lane];
            uint2 ov;
            ov.x = pk2(lrelu(acc0[0] - mp.x), lrelu(acc0[1] - mp.y));
            ov.y = pk2(lrelu(acc0[2] - mp.z), lrelu(acc0[3] - mp.w));
            *(uint2*)((char*)S.h + hoff(r, 8 * lane)) = ov;
        }
        __syncthreads();

        // ---- mid equivariant layers (W -> W), 3x, MFMA ----
        for (int i = 0; i < DD - 2; ++i) {
            colsum<WW, true>(S, tid, lane, wid, Nv, invNv, S.meanh);
            mproj_par<WW, WW>(S, Lmid + (size_t)i * WW * WW, tid);
            eq_gemm_mfma<WW>(S, wsf + (size_t)i * 65536, tid, lane, wid, Nv);
        }

        // ---- last equivariant layer (W -> LAT), MFMA ----
        colsum<WW, true>(S, tid, lane, wid, Nv, invNv, S.meanh);
        mproj_par<WW, LATD>(S, LambdaL, tid);
        eq_gemm_mfma<LATD>(S, wsf + 196608, tid, lane, wid, Nv);

        // ---- pooled = sum over valid rows -> ws ----
        colsum<LATD, false>(S, tid, lane, wid, Nv, invNv, S.meanh);
        if (tid < LATD) pooled[(size_t)b * LATD + tid] = S.meanh[tid];
        __syncthreads();
    }
}

// ---- MLP head over pooled[512][128]: one block per batch row ----
__global__ __launch_bounds__(256) void mlp_kernel(
    const float* __restrict__ pooled,
    const float* __restrict__ F0W, const float* __restrict__ F0b,
    const float* __restrict__ FmidW, const float* __restrict__ Fmidb,
    const float* __restrict__ FlastW, const float* __restrict__ Flastb,
    float* __restrict__ out) {
    __shared__ float yp[LATD];
    __shared__ float y[2][WW];
    const int b = blockIdx.x, tid = threadIdx.x;
    if (tid < LATD) yp[tid] = pooled[(size_t)b * LATD + tid];
    __syncthreads();
    {
        float a = F0b[tid];
        const float* Wp = F0W + tid;
#pragma unroll
        for (int k = 0; k < LATD; ++k) a = fmaf(yp[k], Wp[(size_t)k * WW], a);
        y[0][tid] = lrelu(a);
    }
    __syncthreads();
    int cur = 0;
    for (int i = 0; i < DD - 1; ++i) {
        float a = Fmidb[i * WW + tid];
        const float* Wp = FmidW + (size_t)i * WW * WW + tid;
#pragma unroll
        for (int k = 0; k < WW; ++k) a = fmaf(y[cur][k], Wp[(size_t)k * WW], a);
        y[1 - cur][tid] = lrelu(a);
        __syncthreads();
        cur = 1 - cur;
    }
    if (tid < 64) {
        float a0 = 0.f, a1 = 0.f;
        for (int k = tid; k < WW; k += 64) {
            float yv = y[cur][k];
            a0 = fmaf(yv, FlastW[2 * k], a0);
            a1 = fmaf(yv, FlastW[2 * k + 1], a1);
        }
#pragma unroll
        for (int off = 32; off > 0; off >>= 1) {
            a0 += __shfl_down(a0, off);
            a1 += __shfl_down(a1, off);
        }
        if (tid == 0) {
            a0 += Flastb[0];
            a1 += Flastb[1];
            float m = fmaxf(a0, a1);
            float e0 = expf(a0 - m), e1 = expf(a1 - m);
            float inv = 1.0f / (e0 + e1);
            out[2 * b] = e0 * inv;
            out[2 * b + 1] = e1 * inv;
        }
    }
}

extern "C" void kernel_launch(void* const* d_in, const int* in_sizes, int n_in,
                              void* d_out, int out_size, void* d_ws, size_t ws_size,
                              hipStream_t stream) {
    const float* x = (const float*)d_in[0];
    const float* Gamma0 = (const float*)d_in[1];
    const float* Lambda0 = (const float*)d_in[2];
    const float* Gmid = (const float*)d_in[3];
    const float* Lmid = (const float*)d_in[4];
    const float* GammaL = (const float*)d_in[5];
    const float* LambdaL = (const float*)d_in[6];
    const float* F0W = (const float*)d_in[7];
    const float* F0b = (const float*)d_in[8];
    const float* FmidW = (const float*)d_in[9];
    const float* Fmidb = (const float*)d_in[10];
    const float* FlastW = (const float*)d_in[11];
    const float* Flastb = (const float*)d_in[12];
    float* out = (float*)d_out;

    int* cnt = (int*)d_ws;
    _Float16* wsf = (_Float16*)((char*)d_ws + 16);
    float* pooled = (float*)((char*)d_ws + 458768);

    prep_kernel<<<112, 256, 0, stream>>>(Gmid, GammaL, wsf, cnt);
    deepset_kernel<<<NBLK, NT, 0, stream>>>(x, Gamma0, Lambda0, Lmid, LambdaL,
                                            cnt, wsf, pooled);
    mlp_kernel<<<BB, 256, 0, stream>>>(pooled, F0W, F0b, FmidW, Fmidb, FlastW, Flastb, out);
}